// Round 11
// baseline (412.702 us; speedup 1.0000x reference)
//
#include <hip/hip_runtime.h>
#include <math.h>

#define NB 4
#define NPI 12000
#define NM 32
#define NPTS (NB*NPI*NM)      // 1536000
#define NPIL (NB*NPI)         // 48000

// k_moments config
#define K1_BLOCKS 1500
#define K1_STRIDE (K1_BLOCKS*256)   // 384000
#define K1_ITERS 4                  // NPTS / K1_STRIDE
#define NMOM 54                     // 9 Sf + 45 Sff

// heavy-kernel config: 128 points (4 pillars) per batch, uniform full-32 slots
#define CHUNK 128
#define NBATCH (NPTS/CHUNK)   // 12000
#define SB 1024               // grid for k_stats2
#define LDH 68                // padded h1 row stride (floats)

// ---------------------------------------------------------------- helpers

__device__ __forceinline__ void make_f(float4 v, int4 cc, int np, int m, float zc, float f[9]) {
  const float cx = ((float)cc.w + 0.5f) * 0.16f + 0.0f;
  const float cy = ((float)cc.z + 0.5f) * 0.16f - 39.68f;
  f[0] = v.x; f[1] = v.y; f[2] = v.z; f[3] = v.w;
  f[4] = v.x - cx; f[5] = v.y - cy; f[6] = cx; f[7] = cy; f[8] = zc;
  const float msk = (m < np) ? 1.0f : 0.0f;
#pragma unroll
  for (int i = 0; i < 9; ++i) f[i] *= msk;
}

// ------------------------------------------------- K1: f-moments

__global__ __launch_bounds__(256) void k_moments(
    const float4* __restrict__ vox, const int4* __restrict__ coords,
    const int* __restrict__ npnts, float* __restrict__ P1) {
  const int t = blockIdx.x * 256 + threadIdx.x;
  float acc[NMOM];
#pragma unroll
  for (int v = 0; v < NMOM; ++v) acc[v] = 0.0f;

#pragma unroll
  for (int j = 0; j < K1_ITERS; ++j) {
    const int pt = t + j * K1_STRIDE;
    const int pil = pt >> 5;
    const int m = pt & 31;
    const float4 v = vox[pt];
    const int4 cc = coords[pil];
    const int np = npnts[pil];
    float z = v.z;
#pragma unroll
    for (int s = 1; s < 32; s <<= 1) z += __shfl_xor(z, s, 32);
    const float zc = z * (1.0f / 32.0f);
    float f[9];
    make_f(v, cc, np, m, zc, f);
    int vi = 0;
#pragma unroll
    for (int i = 0; i < 9; ++i) acc[vi++] += f[i];
#pragma unroll
    for (int i = 0; i < 9; ++i)
#pragma unroll
      for (int jj = i; jj < 9; ++jj) acc[vi++] += f[i] * f[jj];
  }

#pragma unroll
  for (int v = 0; v < NMOM; ++v) {
    float x = acc[v];
#pragma unroll
    for (int s = 1; s < 64; s <<= 1) x += __shfl_xor(x, s, 64);
    acc[v] = x;
  }
  __shared__ float red[4][NMOM];
  const int wave = threadIdx.x >> 6, lane = threadIdx.x & 63;
  if (lane == 0) {
#pragma unroll
    for (int v = 0; v < NMOM; ++v) red[wave][v] = acc[v];
  }
  __syncthreads();
  if (threadIdx.x < NMOM) {
    float s = red[0][threadIdx.x] + red[1][threadIdx.x] + red[2][threadIdx.x] + red[3][threadIdx.x];
    P1[threadIdx.x * K1_BLOCKS + blockIdx.x] = s;
  }
}

// ------------------------------------------------- generic row reduce (f32 -> f64)

__global__ __launch_bounds__(256) void k_rowreduce(
    const float* __restrict__ src, double* __restrict__ dst, int ncols) {
  const int row = blockIdx.x;
  const float* p = src + row * ncols;
  double sd = 0.0;
  for (int i = threadIdx.x; i < ncols; i += 256) sd += (double)p[i];
#pragma unroll
  for (int s = 1; s < 64; s <<= 1) sd += __shfl_xor(sd, s, 64);
  __shared__ double rd[4];
  const int wave = threadIdx.x >> 6, lane = threadIdx.x & 63;
  if (lane == 0) rd[wave] = sd;
  __syncthreads();
  if (threadIdx.x == 0) dst[row] = rd[0] + rd[1] + rd[2] + rd[3];
}

// ------------------------------------------------- finalize layer-1 BN params

__global__ void k_fin1(const double* __restrict__ T1, const float* __restrict__ W1,
                       const float* __restrict__ g1, const float* __restrict__ b1,
                       float* __restrict__ params) {
  const int c = threadIdx.x;  // 64
  double w[9];
#pragma unroll
  for (int i = 0; i < 9; ++i) w[i] = (double)W1[i * 64 + c];
  double mean = 0.0;
#pragma unroll
  for (int i = 0; i < 9; ++i) mean += w[i] * T1[i];
  mean /= (double)NPTS;
  double e2 = 0.0;
  int v = 9;
#pragma unroll
  for (int i = 0; i < 9; ++i)
#pragma unroll
    for (int j = i; j < 9; ++j) {
      const double t = T1[v++] * w[i] * w[j];
      e2 += (i == j) ? t : 2.0 * t;
    }
  e2 /= (double)NPTS;
  const double var = e2 - mean * mean;
  const double a = (double)g1[c] / sqrt(var + 0.001);
  params[c] = (float)a;
  params[64 + c] = (float)((double)b1[c] - mean * a);
}

// ------------------------------------------------- K3: layer-2 stats + y2 extreme
// Loop-nest swap kills the register-allocator fight of rounds 7-10: no w2[64]
// invariant array. Outer a4 (rolled, #pragma unroll 1 so W2 loads can't hoist
// into a resident array), inner pp fully unrolled over ALL 32 slots with
// acc[32] (static indexing -> registers). Masked slots compute y2 = y2_0
// exactly as the reference (f=0 -> h1 = relu(b1adj)), so stats and max need
// no mask correction, no sort, no valid-count: fully uniform work.

__global__ __launch_bounds__(256) void k_stats2(
    const float4* __restrict__ vox, const int4* __restrict__ coords,
    const int* __restrict__ npnts, const float* __restrict__ W1,
    const float* __restrict__ W2, const float* __restrict__ g2,
    const float* __restrict__ params, float* __restrict__ P2,
    float* __restrict__ Y2SEL) {
  __shared__ __align__(16) float W1t[9 * 64];
  __shared__ __align__(16) float a1s[64], b1s[64];
  __shared__ __align__(16) float h1s[CHUNK * LDH];
  __shared__ float redS[4][64], redQ[4][64];

  const int t = threadIdx.x;
  for (int i = t; i < 576; i += 256) W1t[i] = W1[i];
  if (t < 64) { a1s[t] = params[t]; b1s[t] = params[64 + t]; }

  const int c = t & 63;
  const float sgn = (g2[c] >= 0.0f) ? 1.0f : -1.0f;
  __syncthreads();

  const int p_loc = t >> 1;
  const int ch_half = (t & 1) * 32;
  const int g = t >> 6;
  float psum = 0.0f, psq = 0.0f;

  for (int bb = blockIdx.x; bb < NBATCH; bb += SB) {
    // ---- phase A: h1 for 128 points (pillars bb*4 .. bb*4+3)
    const int pil = bb * 4 + (p_loc >> 5);
    const int m = p_loc & 31;
    const float4 v = vox[bb * CHUNK + p_loc];
    const int4 cc = coords[pil];
    const int np = npnts[pil];
    float z = v.z;
#pragma unroll
    for (int s = 1; s < 64; s <<= 1) z += __shfl_xor(z, s, 64);  // 32 pts x2 lanes
    const float zc = z * (1.0f / 64.0f);
    float f[9];
    make_f(v, cc, np, m, zc, f);
    float* row = &h1s[p_loc * LDH];
#pragma unroll
    for (int j = 0; j < 8; ++j) {
      const int c0 = ch_half + 4 * j;
      float y0 = 0, y1 = 0, y2 = 0, y3 = 0;
#pragma unroll
      for (int i = 0; i < 9; ++i) {
        const float4 w = *(const float4*)&W1t[i * 64 + c0];
        y0 = fmaf(f[i], w.x, y0);
        y1 = fmaf(f[i], w.y, y1);
        y2 = fmaf(f[i], w.z, y2);
        y3 = fmaf(f[i], w.w, y3);
      }
      const float4 a = *(const float4*)&a1s[c0];
      const float4 b = *(const float4*)&b1s[c0];
      float4 h;
      h.x = fmaxf(fmaf(y0, a.x, b.x), 0.0f);
      h.y = fmaxf(fmaf(y1, a.y, b.y), 0.0f);
      h.z = fmaxf(fmaf(y2, a.z, b.z), 0.0f);
      h.w = fmaxf(fmaf(y3, a.w, b.w), 0.0f);
      *(float4*)&row[c0] = h;
    }
    __syncthreads();
    // ---- phase B: all 32 slots, k-chunk outer / slot inner
    const float* wrow = &h1s[g * 32 * LDH];   // this wave's pillar rows
    float acc[32];
#pragma unroll
    for (int pp = 0; pp < 32; ++pp) acc[pp] = 0.0f;
#pragma unroll 1
    for (int a4 = 0; a4 < 16; ++a4) {
      const float w0 = W2[(4 * a4 + 0) * 64 + c];   // 4 L1-hot scalars,
      const float w1 = W2[(4 * a4 + 1) * 64 + c];   // amortized over 32 slots
      const float w2v = W2[(4 * a4 + 2) * 64 + c];
      const float w3 = W2[(4 * a4 + 3) * 64 + c];
      const float* base = wrow + a4 * 4;
#pragma unroll
      for (int pp = 0; pp < 32; ++pp) {
        const float4 hv = *(const float4*)(base + pp * LDH);  // broadcast read
        float a = acc[pp];
        a = fmaf(hv.x, w0, a);
        a = fmaf(hv.y, w1, a);
        a = fmaf(hv.z, w2v, a);
        a = fmaf(hv.w, w3, a);
        acc[pp] = a;
      }
    }
    float ytr = -INFINITY;
#pragma unroll
    for (int pp = 0; pp < 32; ++pp) {
      const float y = acc[pp];
      psum += y;
      psq = fmaf(y, y, psq);
      ytr = fmaxf(ytr, y * sgn);
    }
    Y2SEL[(bb * 4 + g) * 64 + c] = ytr;   // coalesced (lane = channel)
    __syncthreads();
  }

  const int wave = t >> 6;
  redS[wave][c] = psum;
  redQ[wave][c] = psq;
  __syncthreads();
  if (t < 64) {
    const float s = redS[0][t] + redS[1][t] + redS[2][t] + redS[3][t];
    const float q = redQ[0][t] + redQ[1][t] + redQ[2][t] + redQ[3][t];
    P2[t * SB + blockIdx.x] = s;
    P2[(64 + t) * SB + blockIdx.x] = q;
  }
}

// ------------------------------------------------- finalize layer-2 BN params
// Stats now include every slot (masked included, matching the reference
// definition directly) -- no analytic correction needed.

__global__ void k_fin2(const double* __restrict__ T2, const float* __restrict__ g2,
                       const float* __restrict__ b2, float* __restrict__ params) {
  const int c = threadIdx.x;  // 64
  const double mean = T2[c] / (double)NPTS;
  const double var = T2[64 + c] / (double)NPTS - mean * mean;
  const double a = (double)g2[c] / sqrt(var + 0.001);
  params[128 + c] = (float)a;
  params[192 + c] = (float)((double)b2[c] - mean * a);
}

// ------------------------------------------------- K5: final output pass.
// h2 = relu(a2*y2 + b2adj) monotone in y2; Y2SEL = max(sgn*y2) over all 32
// slots (sgn = sign(g2) = sign(a2)); sel = max(y2) if a2>=0 else min(y2) =
// -Y2SEL (exact negation). Bit-exact vs per-slot evaluation.

__global__ __launch_bounds__(256) void k_final(
    const float* __restrict__ params, const float* __restrict__ Y2SEL,
    float* __restrict__ out) {
  const int idx = blockIdx.x * 256 + threadIdx.x;   // NPIL*64 total
  const int c = idx & 63;
  const float a2 = params[128 + c];
  const float b2 = params[192 + c];
  const float v = Y2SEL[idx];
  const float sel = (a2 >= 0.0f) ? v : -v;
  out[idx] = fmaxf(fmaf(sel, a2, b2), 0.0f);
}

// ---------------------------------------------------------------- launch

extern "C" void kernel_launch(void* const* d_in, const int* in_sizes, int n_in,
                              void* d_out, int out_size, void* d_ws, size_t ws_size,
                              hipStream_t stream) {
  const float4* vox = (const float4*)d_in[0];
  const int4* coords = (const int4*)d_in[1];
  const int* npnts = (const int*)d_in[2];
  const float* W1 = (const float*)d_in[3];
  const float* g1 = (const float*)d_in[4];
  const float* b1 = (const float*)d_in[5];
  const float* W2 = (const float*)d_in[6];
  const float* g2 = (const float*)d_in[7];
  const float* b2 = (const float*)d_in[8];
  float* out = (float*)d_out;

  char* w = (char*)d_ws;
  size_t off = 0;
  double* T1 = (double*)(w + off); off += 512;                 // 54 doubles
  double* T2 = (double*)(w + off); off += 1024;                // 128 doubles
  float* P1 = (float*)(w + off); off += NMOM * K1_BLOCKS * 4;  // 324 KB
  float* P2 = (float*)(w + off); off += 128 * SB * 4;          // 524 KB
  float* params = (float*)(w + off); off += 256 * 4;           // 256 f32
  float* Y2SEL = (float*)(w + off); off += (size_t)NPIL * 64 * 4;  // 12.3 MB

  k_moments<<<K1_BLOCKS, 256, 0, stream>>>(vox, coords, npnts, P1);
  k_rowreduce<<<NMOM, 256, 0, stream>>>(P1, T1, K1_BLOCKS);
  k_fin1<<<1, 64, 0, stream>>>(T1, W1, g1, b1, params);
  k_stats2<<<SB, 256, 0, stream>>>(vox, coords, npnts, W1, W2, g2, params, P2, Y2SEL);
  k_rowreduce<<<128, 256, 0, stream>>>(P2, T2, SB);
  k_fin2<<<1, 64, 0, stream>>>(T2, g2, b2, params);
  k_final<<<(NPIL * 64) / 256, 256, 0, stream>>>(params, Y2SEL, out);
}

// Round 12
// 276.591 us; speedup vs baseline: 1.4921x; 1.4921x over previous
//
#include <hip/hip_runtime.h>
#include <math.h>

#define NB 4
#define NPI 12000
#define NM 32
#define NPTS (NB*NPI*NM)      // 1536000
#define NPIL (NB*NPI)         // 48000

// k_moments config
#define K1_BLOCKS 1500
#define K1_STRIDE (K1_BLOCKS*256)   // 384000
#define K1_ITERS 4                  // NPTS / K1_STRIDE
#define NMOM 55                     // 9 Sf + 45 Sff + 1 valid-count

// heavy-kernel config: 128 points (4 sorted pillars) per batch
#define CHUNK 128
#define NBATCH (NPTS/CHUNK)   // 12000
#define SB 1024               // grid for k_stats2
#define LDH 68                // padded h1 row stride (floats)

// sort config
#define SLICE 188             // 256*188 = 48128 >= NPIL

// ---------------------------------------------------------------- helpers

__device__ __forceinline__ void make_f(float4 v, int4 cc, int np, int m, float zc, float f[9]) {
  const float cx = ((float)cc.w + 0.5f) * 0.16f + 0.0f;
  const float cy = ((float)cc.z + 0.5f) * 0.16f - 39.68f;
  f[0] = v.x; f[1] = v.y; f[2] = v.z; f[3] = v.w;
  f[4] = v.x - cx; f[5] = v.y - cy; f[6] = cx; f[7] = cy; f[8] = zc;
  const float msk = (m < np) ? 1.0f : 0.0f;
#pragma unroll
  for (int i = 0; i < 9; ++i) f[i] *= msk;
}

// ------------------------------------------------- K0: stable counting sort of
// pillars by np (33 bins). Single block, deterministic, loads batched 8-wide.

__global__ __launch_bounds__(256) void k_sort(
    const int* __restrict__ npnts, int* __restrict__ perm) {
  __shared__ int C[33][256];
  __shared__ int T[33], O[33];
  const int t = threadIdx.x;
#pragma unroll
  for (int b = 0; b < 33; ++b) C[b][t] = 0;
  __syncthreads();
  const int i0 = t * SLICE;
  const int i1 = (i0 + SLICE < NPIL) ? i0 + SLICE : NPIL;
  {
    int i = i0;
    for (; i + 8 <= i1; i += 8) {
      int bs[8];
#pragma unroll
      for (int j = 0; j < 8; ++j) bs[j] = npnts[i + j];
#pragma unroll
      for (int j = 0; j < 8; ++j) C[bs[j]][t]++;
    }
    for (; i < i1; ++i) C[npnts[i]][t]++;
  }
  __syncthreads();
  if (t < 33) { int s = 0; for (int j = 0; j < 256; ++j) s += C[t][j]; T[t] = s; }
  __syncthreads();
  if (t == 0) { int r = 0; for (int b = 0; b < 33; ++b) { O[b] = r; r += T[b]; } }
  __syncthreads();
  if (t < 33) {
    int r = O[t];
    for (int j = 0; j < 256; ++j) { const int c = C[t][j]; C[t][j] = r; r += c; }
  }
  __syncthreads();
  {
    int i = i0;
    for (; i + 8 <= i1; i += 8) {
      int bs[8];
#pragma unroll
      for (int j = 0; j < 8; ++j) bs[j] = npnts[i + j];
#pragma unroll
      for (int j = 0; j < 8; ++j) {
        const int b = bs[j];
        const int p = C[b][t];
        C[b][t] = p + 1;
        perm[p] = i + j;
      }
    }
    for (; i < i1; ++i) {
      const int b = npnts[i];
      const int p = C[b][t];
      C[b][t] = p + 1;
      perm[p] = i;
    }
  }
}

// ------------------------------------------------- K1: f-moments + valid count

__global__ __launch_bounds__(256) void k_moments(
    const float4* __restrict__ vox, const int4* __restrict__ coords,
    const int* __restrict__ npnts, float* __restrict__ P1) {
  const int t = blockIdx.x * 256 + threadIdx.x;
  float acc[NMOM];
#pragma unroll
  for (int v = 0; v < NMOM; ++v) acc[v] = 0.0f;

#pragma unroll
  for (int j = 0; j < K1_ITERS; ++j) {
    const int pt = t + j * K1_STRIDE;
    const int pil = pt >> 5;
    const int m = pt & 31;
    const float4 v = vox[pt];
    const int4 cc = coords[pil];
    const int np = npnts[pil];
    float z = v.z;
#pragma unroll
    for (int s = 1; s < 32; s <<= 1) z += __shfl_xor(z, s, 32);
    const float zc = z * (1.0f / 32.0f);
    float f[9];
    make_f(v, cc, np, m, zc, f);
    int vi = 0;
#pragma unroll
    for (int i = 0; i < 9; ++i) acc[vi++] += f[i];
#pragma unroll
    for (int i = 0; i < 9; ++i)
#pragma unroll
      for (int jj = i; jj < 9; ++jj) acc[vi++] += f[i] * f[jj];
    acc[54] += (m < np) ? 1.0f : 0.0f;
  }

#pragma unroll
  for (int v = 0; v < NMOM; ++v) {
    float x = acc[v];
#pragma unroll
    for (int s = 1; s < 64; s <<= 1) x += __shfl_xor(x, s, 64);
    acc[v] = x;
  }
  __shared__ float red[4][NMOM];
  const int wave = threadIdx.x >> 6, lane = threadIdx.x & 63;
  if (lane == 0) {
#pragma unroll
    for (int v = 0; v < NMOM; ++v) red[wave][v] = acc[v];
  }
  __syncthreads();
  if (threadIdx.x < NMOM) {
    float s = red[0][threadIdx.x] + red[1][threadIdx.x] + red[2][threadIdx.x] + red[3][threadIdx.x];
    P1[threadIdx.x * K1_BLOCKS + blockIdx.x] = s;
  }
}

// ------------------------------------------------- generic row reduce (f32 -> f64)

__global__ __launch_bounds__(256) void k_rowreduce(
    const float* __restrict__ src, double* __restrict__ dst, int ncols) {
  const int row = blockIdx.x;
  const float* p = src + row * ncols;
  double sd = 0.0;
  for (int i = threadIdx.x; i < ncols; i += 256) sd += (double)p[i];
#pragma unroll
  for (int s = 1; s < 64; s <<= 1) sd += __shfl_xor(sd, s, 64);
  __shared__ double rd[4];
  const int wave = threadIdx.x >> 6, lane = threadIdx.x & 63;
  if (lane == 0) rd[wave] = sd;
  __syncthreads();
  if (threadIdx.x == 0) dst[row] = rd[0] + rd[1] + rd[2] + rd[3];
}

// ------------------------------------------------- finalize layer-1 BN params

__global__ void k_fin1(const double* __restrict__ T1, const float* __restrict__ W1,
                       const float* __restrict__ g1, const float* __restrict__ b1,
                       float* __restrict__ params) {
  const int c = threadIdx.x;  // 64
  double w[9];
#pragma unroll
  for (int i = 0; i < 9; ++i) w[i] = (double)W1[i * 64 + c];
  double mean = 0.0;
#pragma unroll
  for (int i = 0; i < 9; ++i) mean += w[i] * T1[i];
  mean /= (double)NPTS;
  double e2 = 0.0;
  int v = 9;
#pragma unroll
  for (int i = 0; i < 9; ++i)
#pragma unroll
    for (int j = i; j < 9; ++j) {
      const double t = T1[v++] * w[i] * w[j];
      e2 += (i == j) ? t : 2.0 * t;
    }
  e2 /= (double)NPTS;
  const double var = e2 - mean * mean;
  const double a = (double)g1[c] / sqrt(var + 0.001);
  params[c] = (float)a;
  params[64 + c] = (float)((double)b1[c] - mean * a);
}

// ------------------------------------------------- K3: layer-2 stats + y2 extreme
// R6/R7 structure (the measured optimum: 16 broadcast-b128 + 64 FMA per valid
// point, sorted pillars). The allocator repeatedly demoted w2[64] to cached
// reloads (R7/R8/R10: VGPR 60-68, +70-100us); empty inline-asm "+v" per
// element marks w2 as asm-modified once per pillar -> rematerialization is
// illegal -> w2 stays in VGPRs. launch_bounds(256,2): cap 256, no spill cliff;
// HW still co-schedules 4 waves/SIMD when allocation lands <=128.

__global__ __launch_bounds__(256, 2) void k_stats2(
    const float4* __restrict__ vox, const int4* __restrict__ coords,
    const int* __restrict__ npnts, const float* __restrict__ W1,
    const float* __restrict__ W2, const float* __restrict__ g2,
    const float* __restrict__ params, const int* __restrict__ perm,
    float* __restrict__ P2, float* __restrict__ Y2SEL) {
  __shared__ __align__(16) float W1t[9 * 64];
  __shared__ __align__(16) float a1s[64], b1s[64];
  __shared__ __align__(16) float h1s[CHUNK * LDH];
  __shared__ float redS[4][64], redQ[4][64];

  const int t = threadIdx.x;
  for (int i = t; i < 576; i += 256) W1t[i] = W1[i];
  if (t < 64) { a1s[t] = params[t]; b1s[t] = params[64 + t]; }

  const int c = t & 63;
  float w2[64];
#pragma unroll
  for (int k = 0; k < 64; ++k) w2[k] = W2[k * 64 + c];
  const float sgn = (g2[c] >= 0.0f) ? 1.0f : -1.0f;
  __syncthreads();

  const int p_loc = t >> 1;
  const int ch_half = (t & 1) * 32;
  const int g = t >> 6;
  float psum = 0.0f, psq = 0.0f;

  for (int bb = blockIdx.x; bb < NBATCH; bb += SB) {
    // ---- pin w2 in VGPRs for this iteration (0 instructions emitted)
#pragma unroll
    for (int k = 0; k < 64; ++k) asm volatile("" : "+v"(w2[k]));
    // ---- phase A: h1 for 128 points (4 permuted pillars)
    const int pid = perm[bb * 4 + (p_loc >> 5)];
    const int m = p_loc & 31;
    const float4 v = vox[pid * 32 + m];
    const int4 cc = coords[pid];
    const int np = npnts[pid];
    float z = v.z;
#pragma unroll
    for (int s = 1; s < 64; s <<= 1) z += __shfl_xor(z, s, 64);  // 32 pts x2 lanes
    const float zc = z * (1.0f / 64.0f);
    float f[9];
    make_f(v, cc, np, m, zc, f);
    float* row = &h1s[p_loc * LDH];
#pragma unroll
    for (int j = 0; j < 8; ++j) {
      const int c0 = ch_half + 4 * j;
      float y0 = 0, y1 = 0, y2 = 0, y3 = 0;
#pragma unroll
      for (int i = 0; i < 9; ++i) {
        const float4 w = *(const float4*)&W1t[i * 64 + c0];
        y0 = fmaf(f[i], w.x, y0);
        y1 = fmaf(f[i], w.y, y1);
        y2 = fmaf(f[i], w.z, y2);
        y3 = fmaf(f[i], w.w, y3);
      }
      const float4 a = *(const float4*)&a1s[c0];
      const float4 b = *(const float4*)&b1s[c0];
      float4 h;
      h.x = fmaxf(fmaf(y0, a.x, b.x), 0.0f);
      h.y = fmaxf(fmaf(y1, a.y, b.y), 0.0f);
      h.z = fmaxf(fmaf(y2, a.z, b.z), 0.0f);
      h.w = fmaxf(fmaf(y3, a.w, b.w), 0.0f);
      *(float4*)&row[c0] = h;
    }
    __syncthreads();
    // ---- phase B: valid points only (np_g wave-uniform; sorted -> max ~= mean)
    const int pidB = perm[bb * 4 + g];
    const int np_g = npnts[pidB];
    float ytr = -INFINITY;
#pragma unroll 2
    for (int pp = 0; pp < np_g; ++pp) {
      const float4* hr = (const float4*)&h1s[(g * 32 + pp) * LDH];
      float y0 = 0, y1 = 0, y2 = 0, y3 = 0;
#pragma unroll
      for (int a4 = 0; a4 < 16; ++a4) {
        const float4 hv = hr[a4];   // broadcast read
        y0 = fmaf(hv.x, w2[4 * a4 + 0], y0);
        y1 = fmaf(hv.y, w2[4 * a4 + 1], y1);
        y2 = fmaf(hv.z, w2[4 * a4 + 2], y2);
        y3 = fmaf(hv.w, w2[4 * a4 + 3], y3);
      }
      const float y = (y0 + y1) + (y2 + y3);
      psum += y;
      psq = fmaf(y, y, psq);
      ytr = fmaxf(ytr, y * sgn);
    }
    Y2SEL[pidB * 64 + c] = ytr;   // coalesced (lane = channel)
    __syncthreads();
  }

  const int wave = t >> 6;
  redS[wave][c] = psum;
  redQ[wave][c] = psq;
  __syncthreads();
  if (t < 64) {
    const float s = redS[0][t] + redS[1][t] + redS[2][t] + redS[3][t];
    const float q = redQ[0][t] + redQ[1][t] + redQ[2][t] + redQ[3][t];
    P2[t * SB + blockIdx.x] = s;
    P2[(64 + t) * SB + blockIdx.x] = q;
  }
}

// ------------------------------------------------- finalize layer-2 BN params
// Adds masked-point contributions in closed form; precomputes h2_0 for k_final.

__global__ void k_fin2(const double* __restrict__ T2, const float* __restrict__ g2,
                       const float* __restrict__ b2, const float* __restrict__ W2,
                       const double* __restrict__ T1, float* __restrict__ params) {
  const int c = threadIdx.x;  // 64
  const double nmask = (double)NPTS - T1[54];
  double y20 = 0.0;
  for (int k = 0; k < 64; ++k) {
    const float h0 = fmaxf(params[64 + k], 0.0f);   // h1_0[k] = relu(b1adj[k])
    y20 += (double)h0 * (double)W2[k * 64 + c];
  }
  const double sum = T2[c] + nmask * y20;
  const double sq  = T2[64 + c] + nmask * y20 * y20;
  const double mean = sum / (double)NPTS;
  const double var = sq / (double)NPTS - mean * mean;
  const double a = (double)g2[c] / sqrt(var + 0.001);
  const double badj = (double)b2[c] - mean * a;
  params[128 + c] = (float)a;
  params[192 + c] = (float)badj;
  params[256 + c] = (float)fmax(a * y20 + badj, 0.0);   // h2_0[c] (relu)
}

// ------------------------------------------------- K5: final output pass.
// h2 = relu(a2*y2 + b2adj) monotone in y2; Y2SEL = max(sgn*y2) over valid
// points (sgn = sign(g2) = sign(a2)); sel = max(y2) if a2>=0 else min(y2) =
// -Y2SEL (exact negation). Masked slots fold in as h2_0. Bit-exact.

__global__ __launch_bounds__(256) void k_final(
    const int* __restrict__ npnts, const float* __restrict__ params,
    const float* __restrict__ Y2SEL, float* __restrict__ out) {
  const int idx = blockIdx.x * 256 + threadIdx.x;   // NPIL*64 total
  const int pid = idx >> 6;
  const int c = idx & 63;
  const int np = npnts[pid];
  const float a2 = params[128 + c];
  const float b2 = params[192 + c];
  const float h20 = params[256 + c];
  const float v = Y2SEL[idx];
  const float sel = (a2 >= 0.0f) ? v : -v;
  float h = (np > 0) ? fmaxf(fmaf(sel, a2, b2), 0.0f) : 0.0f;
  if (np < 32) h = fmaxf(h, h20);
  out[idx] = h;
}

// ---------------------------------------------------------------- launch

extern "C" void kernel_launch(void* const* d_in, const int* in_sizes, int n_in,
                              void* d_out, int out_size, void* d_ws, size_t ws_size,
                              hipStream_t stream) {
  const float4* vox = (const float4*)d_in[0];
  const int4* coords = (const int4*)d_in[1];
  const int* npnts = (const int*)d_in[2];
  const float* W1 = (const float*)d_in[3];
  const float* g1 = (const float*)d_in[4];
  const float* b1 = (const float*)d_in[5];
  const float* W2 = (const float*)d_in[6];
  const float* g2 = (const float*)d_in[7];
  const float* b2 = (const float*)d_in[8];
  float* out = (float*)d_out;

  char* w = (char*)d_ws;
  size_t off = 0;
  double* T1 = (double*)(w + off); off += 512;                 // 55 doubles
  double* T2 = (double*)(w + off); off += 1024;                // 128 doubles
  float* P1 = (float*)(w + off); off += NMOM * K1_BLOCKS * 4;  // 330 KB
  float* P2 = (float*)(w + off); off += 128 * SB * 4;          // 524 KB
  float* params = (float*)(w + off); off += 512 * 4;           // 320 used
  int* perm = (int*)(w + off); off += NPIL * 4;                // 192 KB
  float* Y2SEL = (float*)(w + off); off += (size_t)NPIL * 64 * 4;  // 12.3 MB

  k_sort<<<1, 256, 0, stream>>>(npnts, perm);
  k_moments<<<K1_BLOCKS, 256, 0, stream>>>(vox, coords, npnts, P1);
  k_rowreduce<<<NMOM, 256, 0, stream>>>(P1, T1, K1_BLOCKS);
  k_fin1<<<1, 64, 0, stream>>>(T1, W1, g1, b1, params);
  k_stats2<<<SB, 256, 0, stream>>>(vox, coords, npnts, W1, W2, g2, params, perm, P2, Y2SEL);
  k_rowreduce<<<128, 256, 0, stream>>>(P2, T2, SB);
  k_fin2<<<1, 64, 0, stream>>>(T2, g2, b2, W2, T1, params);
  k_final<<<(NPIL * 64) / 256, 256, 0, stream>>>(npnts, params, Y2SEL, out);
}

// Round 13
// 172.986 us; speedup vs baseline: 2.3857x; 1.5989x over previous
//
#include <hip/hip_runtime.h>
#include <math.h>

#define NB 4
#define NPI 12000
#define NM 32
#define NPTS (NB*NPI*NM)      // 1536000
#define NPIL (NB*NPI)         // 48000

// k_moments config
#define K1_BLOCKS 1500
#define K1_STRIDE (K1_BLOCKS*256)   // 384000
#define K1_ITERS 4                  // NPTS / K1_STRIDE
#define NMOM 54                     // 9 Sf + 45 Sff (no valid-count needed)

// heavy-kernel config: 128 points (4 pillars) per batch, all-32-slots uniform
#define CHUNK 128
#define NBATCH (NPTS/CHUNK)   // 12000
#define SB 512                // 2 blocks/CU resident (LDS ~59KB)
#define LDB 72                // bf16 row stride: 144B = 9*16B (16B-aligned rows)

typedef __attribute__((ext_vector_type(8))) short bfrag;     // 8 bf16 = 4 VGPRs
typedef __attribute__((ext_vector_type(16))) float f32x16;   // MFMA 32x32 acc

// ---------------------------------------------------------------- helpers

__device__ __forceinline__ void make_f(float4 v, int4 cc, int np, int m, float zc, float f[9]) {
  const float cx = ((float)cc.w + 0.5f) * 0.16f + 0.0f;
  const float cy = ((float)cc.z + 0.5f) * 0.16f - 39.68f;
  f[0] = v.x; f[1] = v.y; f[2] = v.z; f[3] = v.w;
  f[4] = v.x - cx; f[5] = v.y - cy; f[6] = cx; f[7] = cy; f[8] = zc;
  const float msk = (m < np) ? 1.0f : 0.0f;
#pragma unroll
  for (int i = 0; i < 9; ++i) f[i] *= msk;
}

// ------------------------------------------------- K1: f-moments

__global__ __launch_bounds__(256) void k_moments(
    const float4* __restrict__ vox, const int4* __restrict__ coords,
    const int* __restrict__ npnts, float* __restrict__ P1) {
  const int t = blockIdx.x * 256 + threadIdx.x;
  float acc[NMOM];
#pragma unroll
  for (int v = 0; v < NMOM; ++v) acc[v] = 0.0f;

#pragma unroll
  for (int j = 0; j < K1_ITERS; ++j) {
    const int pt = t + j * K1_STRIDE;
    const int pil = pt >> 5;
    const int m = pt & 31;
    const float4 v = vox[pt];
    const int4 cc = coords[pil];
    const int np = npnts[pil];
    float z = v.z;
#pragma unroll
    for (int s = 1; s < 32; s <<= 1) z += __shfl_xor(z, s, 32);
    const float zc = z * (1.0f / 32.0f);
    float f[9];
    make_f(v, cc, np, m, zc, f);
    int vi = 0;
#pragma unroll
    for (int i = 0; i < 9; ++i) acc[vi++] += f[i];
#pragma unroll
    for (int i = 0; i < 9; ++i)
#pragma unroll
      for (int jj = i; jj < 9; ++jj) acc[vi++] += f[i] * f[jj];
  }

#pragma unroll
  for (int v = 0; v < NMOM; ++v) {
    float x = acc[v];
#pragma unroll
    for (int s = 1; s < 64; s <<= 1) x += __shfl_xor(x, s, 64);
    acc[v] = x;
  }
  __shared__ float red[4][NMOM];
  const int wave = threadIdx.x >> 6, lane = threadIdx.x & 63;
  if (lane == 0) {
#pragma unroll
    for (int v = 0; v < NMOM; ++v) red[wave][v] = acc[v];
  }
  __syncthreads();
  if (threadIdx.x < NMOM) {
    float s = red[0][threadIdx.x] + red[1][threadIdx.x] + red[2][threadIdx.x] + red[3][threadIdx.x];
    P1[threadIdx.x * K1_BLOCKS + blockIdx.x] = s;
  }
}

// ------------------------------------------------- generic row reduce (f32 -> f64)

__global__ __launch_bounds__(256) void k_rowreduce(
    const float* __restrict__ src, double* __restrict__ dst, int ncols) {
  const int row = blockIdx.x;
  const float* p = src + row * ncols;
  double sd = 0.0;
  for (int i = threadIdx.x; i < ncols; i += 256) sd += (double)p[i];
#pragma unroll
  for (int s = 1; s < 64; s <<= 1) sd += __shfl_xor(sd, s, 64);
  __shared__ double rd[4];
  const int wave = threadIdx.x >> 6, lane = threadIdx.x & 63;
  if (lane == 0) rd[wave] = sd;
  __syncthreads();
  if (threadIdx.x == 0) dst[row] = rd[0] + rd[1] + rd[2] + rd[3];
}

// ------------------------------------------------- finalize layer-1 BN params

__global__ void k_fin1(const double* __restrict__ T1, const float* __restrict__ W1,
                       const float* __restrict__ g1, const float* __restrict__ b1,
                       float* __restrict__ params) {
  const int c = threadIdx.x;  // 64
  double w[9];
#pragma unroll
  for (int i = 0; i < 9; ++i) w[i] = (double)W1[i * 64 + c];
  double mean = 0.0;
#pragma unroll
  for (int i = 0; i < 9; ++i) mean += w[i] * T1[i];
  mean /= (double)NPTS;
  double e2 = 0.0;
  int v = 9;
#pragma unroll
  for (int i = 0; i < 9; ++i)
#pragma unroll
    for (int j = i; j < 9; ++j) {
      const double t = T1[v++] * w[i] * w[j];
      e2 += (i == j) ? t : 2.0 * t;
    }
  e2 /= (double)NPTS;
  const double var = e2 - mean * mean;
  const double a = (double)g1[c] / sqrt(var + 0.001);
  params[c] = (float)a;
  params[64 + c] = (float)((double)b1[c] - mean * a);
}

// ------------------------------------------------- K3: layer-2 via MFMA
// Phase B is a (32pts x 64k)@(64k x 64ch) GEMM per pillar -> matrix pipe.
// Split-bf16 (trunc): x = hi + lo exactly-representable residual; y2 =
// Ahi*Bhi + Ahi*Blo + Alo*Bhi, err ~2^-15 rel (~1e-4 abs). MFMA operands
// read per-use from LDS (1 ds_read_b128 each) -> nothing the allocator can
// demote (rounds 7-12 lesson); accumulators are MFMA C/D (not remat-able).
// All 32 slots processed uniformly: masked slots contribute y2_0 to stats
// and h2_0 to the max EXACTLY as the reference does -> no sort, no
// valid-count, no corrections, no barriers in the main loop (each wave
// produces and consumes its own pillar's LDS rows).
// C layout (verified): col=lane&31, row=(reg&3)+8*(reg>>2)+4*(lane>>5).
// A/B layout (standard): row/col=lane&31, k = 8*(lane>>5)+e, e in mem order.

__global__ __launch_bounds__(256) void k_stats2(
    const float4* __restrict__ vox, const int4* __restrict__ coords,
    const int* __restrict__ npnts, const float* __restrict__ W1,
    const float* __restrict__ W2, const float* __restrict__ g2,
    const float* __restrict__ params, float* __restrict__ P2,
    float* __restrict__ Y2SEL) {
  __shared__ __align__(16) float W1t[9 * 64];
  __shared__ __align__(16) float a1s[64], b1s[64];
  __shared__ __align__(16) unsigned short h1hi[128][LDB];   // 18432 B
  __shared__ __align__(16) unsigned short h1lo[128][LDB];   // 18432 B
  __shared__ __align__(16) unsigned short W2Thi[64][LDB];   //  9216 B
  __shared__ __align__(16) unsigned short W2Tlo[64][LDB];   //  9216 B
  __shared__ float redS[4][64], redQ[4][64];

  const int t = threadIdx.x;
  for (int i = t; i < 576; i += 256) W1t[i] = W1[i];
  if (t < 64) { a1s[t] = params[t]; b1s[t] = params[64 + t]; }
  // stage W2^T split into LDS (one-time): W2T[out_ch][k]
  for (int i = t; i < 4096; i += 256) {
    const int k = i >> 6, c = i & 63;
    const float x = W2[i];
    const unsigned int b = __float_as_uint(x);
    W2Thi[c][k] = (unsigned short)(b >> 16);
    const float r = x - __uint_as_float(b & 0xFFFF0000u);
    W2Tlo[c][k] = (unsigned short)(__float_as_uint(r) >> 16);
  }

  const int lane = t & 63;
  const int wv = t >> 6;
  const float sg0 = (g2[lane & 31] >= 0.0f) ? 1.0f : -1.0f;        // tile0 ch
  const float sg1 = (g2[32 + (lane & 31)] >= 0.0f) ? 1.0f : -1.0f; // tile1 ch
  __syncthreads();

  const int p_loc = t >> 1;             // phase-A point 0..127 (wave wv owns pillar wv)
  const int ch_half = (t & 1) * 32;
  const int arow = 32 * wv + (lane & 31);   // A-frag h1 row
  const int koff = 8 * (lane >> 5);         // k base within 16-step
  const int bcol = lane & 31;               // B-frag W2T row (tile0)
  float psum = 0.0f, psq = 0.0f;

  for (int bb = blockIdx.x; bb < NBATCH; bb += SB) {
    // ---- phase A: h1 (f32) -> split bf16 hi/lo in LDS, for this wave's pillar
    const int pil = bb * 4 + (p_loc >> 5);
    const int m = p_loc & 31;
    const float4 v = vox[bb * CHUNK + p_loc];
    const int4 cc = coords[pil];
    const int np = npnts[pil];
    float z = v.z;
#pragma unroll
    for (int s = 1; s < 64; s <<= 1) z += __shfl_xor(z, s, 64);  // 32 pts x2 lanes
    const float zc = z * (1.0f / 64.0f);
    float f[9];
    make_f(v, cc, np, m, zc, f);
#pragma unroll
    for (int j = 0; j < 8; ++j) {
      const int c0 = ch_half + 4 * j;
      float y0 = 0, y1 = 0, y2 = 0, y3 = 0;
#pragma unroll
      for (int i = 0; i < 9; ++i) {
        const float4 w = *(const float4*)&W1t[i * 64 + c0];
        y0 = fmaf(f[i], w.x, y0);
        y1 = fmaf(f[i], w.y, y1);
        y2 = fmaf(f[i], w.z, y2);
        y3 = fmaf(f[i], w.w, y3);
      }
      const float4 a = *(const float4*)&a1s[c0];
      const float4 b = *(const float4*)&b1s[c0];
      float4 h;
      h.x = fmaxf(fmaf(y0, a.x, b.x), 0.0f);
      h.y = fmaxf(fmaf(y1, a.y, b.y), 0.0f);
      h.z = fmaxf(fmaf(y2, a.z, b.z), 0.0f);
      h.w = fmaxf(fmaf(y3, a.w, b.w), 0.0f);
      // trunc-split to bf16 hi/lo (exact residuals, pure bit ops)
      const unsigned int bx = __float_as_uint(h.x), by = __float_as_uint(h.y);
      const unsigned int bz = __float_as_uint(h.z), bw = __float_as_uint(h.w);
      uint2 hiw, low;
      hiw.x = (bx >> 16) | (by & 0xFFFF0000u);
      hiw.y = (bz >> 16) | (bw & 0xFFFF0000u);
      const float rx = h.x - __uint_as_float(bx & 0xFFFF0000u);
      const float ry = h.y - __uint_as_float(by & 0xFFFF0000u);
      const float rz = h.z - __uint_as_float(bz & 0xFFFF0000u);
      const float rw = h.w - __uint_as_float(bw & 0xFFFF0000u);
      low.x = (__float_as_uint(rx) >> 16) | (__float_as_uint(ry) & 0xFFFF0000u);
      low.y = (__float_as_uint(rz) >> 16) | (__float_as_uint(rw) & 0xFFFF0000u);
      *(uint2*)&h1hi[p_loc][c0] = hiw;
      *(uint2*)&h1lo[p_loc][c0] = low;
    }
    // no barrier: wave wv wrote rows 32wv..32wv+31 and reads only those
    // (within-wave DS ordering; compiler inserts lgkmcnt waits)

    // ---- phase B: y2 = h1 @ W2 via 3-term split-bf16 MFMA, 2 channel-tiles
    f32x16 acc0, acc1;
#pragma unroll
    for (int i = 0; i < 16; ++i) { acc0[i] = 0.0f; acc1[i] = 0.0f; }
#pragma unroll
    for (int ks = 0; ks < 4; ++ks) {
      const int kk = koff + 16 * ks;
      const bfrag ahi = *(const bfrag*)&h1hi[arow][kk];
      const bfrag alo = *(const bfrag*)&h1lo[arow][kk];
      const bfrag bhi0 = *(const bfrag*)&W2Thi[bcol][kk];
      const bfrag blo0 = *(const bfrag*)&W2Tlo[bcol][kk];
      const bfrag bhi1 = *(const bfrag*)&W2Thi[bcol + 32][kk];
      const bfrag blo1 = *(const bfrag*)&W2Tlo[bcol + 32][kk];
      acc0 = __builtin_amdgcn_mfma_f32_32x32x16_bf16(ahi, bhi0, acc0, 0, 0, 0);
      acc1 = __builtin_amdgcn_mfma_f32_32x32x16_bf16(ahi, bhi1, acc1, 0, 0, 0);
      acc0 = __builtin_amdgcn_mfma_f32_32x32x16_bf16(ahi, blo0, acc0, 0, 0, 0);
      acc1 = __builtin_amdgcn_mfma_f32_32x32x16_bf16(ahi, blo1, acc1, 0, 0, 0);
      acc0 = __builtin_amdgcn_mfma_f32_32x32x16_bf16(alo, bhi0, acc0, 0, 0, 0);
      acc1 = __builtin_amdgcn_mfma_f32_32x32x16_bf16(alo, bhi1, acc1, 0, 0, 0);
    }
    // ---- epilogue: rows=points live in 16 regs + partner lane (lane^32)
    float s0 = 0, q0 = 0, m0 = -INFINITY, s1 = 0, q1 = 0, m1 = -INFINITY;
#pragma unroll
    for (int i = 0; i < 16; ++i) {
      const float v0 = acc0[i], v1 = acc1[i];
      s0 += v0; q0 = fmaf(v0, v0, q0); m0 = fmaxf(m0, v0 * sg0);
      s1 += v1; q1 = fmaf(v1, v1, q1); m1 = fmaxf(m1, v1 * sg1);
    }
    s0 += __shfl_xor(s0, 32, 64); q0 += __shfl_xor(q0, 32, 64);
    m0 = fmaxf(m0, __shfl_xor(m0, 32, 64));
    s1 += __shfl_xor(s1, 32, 64); q1 += __shfl_xor(q1, 32, 64);
    m1 = fmaxf(m1, __shfl_xor(m1, 32, 64));
    const bool hiHalf = lane >= 32;   // lane's own channel = lane
    psum += hiHalf ? s1 : s0;
    psq += hiHalf ? q1 : q0;
    Y2SEL[(bb * 4 + wv) * 64 + lane] = hiHalf ? m1 : m0;   // coalesced
  }

  redS[wv][lane] = psum;
  redQ[wv][lane] = psq;
  __syncthreads();
  if (t < 64) {
    const float s = redS[0][t] + redS[1][t] + redS[2][t] + redS[3][t];
    const float q = redQ[0][t] + redQ[1][t] + redQ[2][t] + redQ[3][t];
    P2[t * SB + blockIdx.x] = s;
    P2[(64 + t) * SB + blockIdx.x] = q;
  }
}

// ------------------------------------------------- finalize layer-2 BN params
// Stats include every slot (masked slots contribute y2_0), matching the
// reference BN definition directly -- no correction.

__global__ void k_fin2(const double* __restrict__ T2, const float* __restrict__ g2,
                       const float* __restrict__ b2, float* __restrict__ params) {
  const int c = threadIdx.x;  // 64
  const double mean = T2[c] / (double)NPTS;
  const double var = T2[64 + c] / (double)NPTS - mean * mean;
  const double a = (double)g2[c] / sqrt(var + 0.001);
  params[128 + c] = (float)a;
  params[192 + c] = (float)((double)b2[c] - mean * a);
}

// ------------------------------------------------- K5: final output pass.
// h2 = relu(a2*y2 + b2adj) monotone in y2; Y2SEL = max(sgn*y2) over all 32
// slots (sgn = sign(g2) = sign(a2)); sel = max(y2) if a2>=0 else min(y2) =
// -Y2SEL (exact negation). Masked slots participated naturally.

__global__ __launch_bounds__(256) void k_final(
    const float* __restrict__ params, const float* __restrict__ Y2SEL,
    float* __restrict__ out) {
  const int idx = blockIdx.x * 256 + threadIdx.x;   // NPIL*64 total
  const int c = idx & 63;
  const float a2 = params[128 + c];
  const float b2 = params[192 + c];
  const float v = Y2SEL[idx];
  const float sel = (a2 >= 0.0f) ? v : -v;
  out[idx] = fmaxf(fmaf(sel, a2, b2), 0.0f);
}

// ---------------------------------------------------------------- launch

extern "C" void kernel_launch(void* const* d_in, const int* in_sizes, int n_in,
                              void* d_out, int out_size, void* d_ws, size_t ws_size,
                              hipStream_t stream) {
  const float4* vox = (const float4*)d_in[0];
  const int4* coords = (const int4*)d_in[1];
  const int* npnts = (const int*)d_in[2];
  const float* W1 = (const float*)d_in[3];
  const float* g1 = (const float*)d_in[4];
  const float* b1 = (const float*)d_in[5];
  const float* W2 = (const float*)d_in[6];
  const float* g2 = (const float*)d_in[7];
  const float* b2 = (const float*)d_in[8];
  float* out = (float*)d_out;

  char* w = (char*)d_ws;
  size_t off = 0;
  double* T1 = (double*)(w + off); off += 512;                 // 54 doubles
  double* T2 = (double*)(w + off); off += 1024;                // 128 doubles
  float* P1 = (float*)(w + off); off += NMOM * K1_BLOCKS * 4;  // 324 KB
  float* P2 = (float*)(w + off); off += 128 * SB * 4;          // 262 KB
  float* params = (float*)(w + off); off += 256 * 4;           // 256 f32
  float* Y2SEL = (float*)(w + off); off += (size_t)NPIL * 64 * 4;  // 12.3 MB

  k_moments<<<K1_BLOCKS, 256, 0, stream>>>(vox, coords, npnts, P1);
  k_rowreduce<<<NMOM, 256, 0, stream>>>(P1, T1, K1_BLOCKS);
  k_fin1<<<1, 64, 0, stream>>>(T1, W1, g1, b1, params);
  k_stats2<<<SB, 256, 0, stream>>>(vox, coords, npnts, W1, W2, g2, params, P2, Y2SEL);
  k_rowreduce<<<128, 256, 0, stream>>>(P2, T2, SB);
  k_fin2<<<1, 64, 0, stream>>>(T2, g2, b2, params);
  k_final<<<(NPIL * 64) / 256, 256, 0, stream>>>(params, Y2SEL, out);
}